// Round 4
// baseline (101.447 us; speedup 1.0000x reference)
//
#include <hip/hip_runtime.h>
#include <cstdint>
#include <climits>

#define GRID_N 16777216
#define N_STEPS 100
#define NCAND (2 * N_STEPS + 1)   // 200 boundary-origin candidates + c0
#define SUMBLKS 2048

// nan_to_num(psi, nan=0.0, posinf=1.0, neginf=-1.0)
__device__ __forceinline__ float fixv(float v) {
    if (isnan(v)) return 0.0f;
    if (isinf(v)) return v > 0.0f ? 1.0f : -1.0f;
    return v;
}

// psi0*psi0 + psi1*psi1 in strict f32, no FMA contraction (match host semantics)
__device__ __forceinline__ float raw_prob(float a, float b) {
    return __fadd_rn(__fmul_rn(a, a), __fmul_rn(b, b));
}

// x86 cvttss2si semantics: out-of-range or NaN -> INT_MIN (NOT GPU saturation)
__device__ __forceinline__ int host_f2i(float sf) {
    if (!(sf >= -2147483648.0f && sf < 2147483648.0f)) return INT_MIN;
    return (int)sf;
}

__device__ __forceinline__ int wrap_clip(int c, int shift) {
    int r = (int)((unsigned)c + (unsigned)shift);  // int32 wrapping add (XLA/NumPy)
    if (r < 0) r = 0;
    if (r > GRID_N - 1) r = GRID_N - 1;
    return r;
}

__global__ __launch_bounds__(256) void qpe_fused_kernel(const float* __restrict__ psi,
                                                        const float* __restrict__ noise,
                                                        const float* __restrict__ x,
                                                        const int* __restrict__ c0p,
                                                        unsigned int* __restrict__ counter,
                                                        double* __restrict__ partials,
                                                        float* __restrict__ out) {
    const int tid = threadIdx.x;
    const int bid = blockIdx.x;

    if (bid != 0) {
        // ---------- sum block: slice (bid-1), identical partition to r3 ----------
        const float4* psi4 = (const float4*)psi;
        const int n4 = GRID_N / 2;
        double acc = 0.0;
        const int stride = SUMBLKS * 256;
        for (int i = (bid - 1) * 256 + tid; i < n4; i += stride) {
            float4 v = psi4[i];
            acc += (double)raw_prob(fixv(v.x), fixv(v.y));
            acc += (double)raw_prob(fixv(v.z), fixv(v.w));
        }
        __shared__ double sm[256];
        sm[tid] = acc;
        __syncthreads();
        for (int s = 128; s > 0; s >>= 1) {   // fixed-order tree -> deterministic
            if (tid < s) sm[tid] += sm[tid + s];
            __syncthreads();
        }
        if (tid == 0) {
            // agent-scope release publish (XCD L2s are not coherent)
            __hip_atomic_store(&partials[bid - 1], sm[0], __ATOMIC_RELEASE,
                               __HIP_MEMORY_SCOPE_AGENT);
            __hip_atomic_fetch_add(counter, 1u, __ATOMIC_RELEASE,
                                   __HIP_MEMORY_SCOPE_AGENT);
        }
        return;
    }

    // ---------------- block 0: prep -> wait -> reduce -> walk ----------------
    const float DXf    = (float)(20.0 / (double)(GRID_N - 1));
    const float TWODXf = (float)(2.0 * (20.0 / (double)(GRID_N - 1)));
    const float DTf    = 0.01f;
    const float SQ2DTf = (float)0.14142135623730950488;  // np.sqrt(0.02) -> f32

    __shared__ int    cand_c[256];
    __shared__ float  cand_s[256];
    __shared__ double red[256];
    __shared__ float  norm_sh;

    // phase A: candidate positions; issue psi loads NOW (latency hides under sum)
    int myc = -1;
    float2 lo = make_float2(0.0f, 0.0f), hi = make_float2(0.0f, 0.0f);
    if (tid < NCAND) {
        if (tid == NCAND - 1) {
            myc = *c0p;
        } else {
            int t = tid >> 1;
            float n = noise[t];
            // identical fp sequence to a walk step with s==0:
            float move = __fadd_rn(__fmul_rn(0.0f, DTf), __fmul_rn(n, SQ2DTf));
            if (!isfinite(move)) move = 0.0f;
            int shift = host_f2i(__fdiv_rn(move, DXf));
            int b = (tid & 1) ? (GRID_N - 1) : 0;
            myc = wrap_clip(b, shift);
        }
        if (myc > 0 && myc < GRID_N - 1) {
            lo = *(const float2*)(psi + 2 * myc - 2);  // psi[c-1][0..1]
            hi = *(const float2*)(psi + 2 * myc + 2);  // psi[c+1][0..1]
        }
    }

    // wait for all sum blocks (they never wait on us -> no deadlock)
    if (tid == 0) {
        while (__hip_atomic_load(counter, __ATOMIC_ACQUIRE,
                                 __HIP_MEMORY_SCOPE_AGENT) < SUMBLKS) {
            __builtin_amdgcn_s_sleep(8);
        }
    }
    __syncthreads();

    // phase B: deterministic fixed-order f64 reduce (agent-scope loads)
    double acc = 0.0;
    for (int i = tid; i < SUMBLKS; i += 256)
        acc += __hip_atomic_load(&partials[i], __ATOMIC_RELAXED,
                                 __HIP_MEMORY_SCOPE_AGENT);
    red[tid] = acc;
    __syncthreads();
    for (int s = 128; s > 0; s >>= 1) {
        if (tid < s) red[tid] += red[tid + s];
        __syncthreads();
    }
    if (tid == 0) {
        float S = (float)red[0];
        norm_sh = __fadd_rn(__fmul_rn(S, DXf), 1e-8f);
    }
    __syncthreads();
    float norm = norm_sh;

    // phase C: per-candidate score -> LDS table (exact ref fp sequence)
    float s_val = 0.0f;
    if (tid < NCAND && myc > 0 && myc < GRID_N - 1) {
        float a0 = fixv(lo.x), b0 = fixv(lo.y);
        float a1 = fixv(hi.x), b1 = fixv(hi.y);
        float p1 = fmaxf(__fdiv_rn(raw_prob(a1, b1), norm), 1e-12f);
        float p0 = fmaxf(__fdiv_rn(raw_prob(a0, b0), norm), 1e-12f);
        s_val = __fdiv_rn(__fsub_rn(logf(p1), logf(p0)), TWODXf);
    }
    cand_c[tid] = (tid < NCAND) ? myc : -1;
    cand_s[tid] = s_val;
    __syncthreads();

    if (tid != 0) return;

    // phase D: sequential walk, LDS table lookups
    int c = cand_c[NCAND - 1];   // == *c0p
    int pred = NCAND - 1;        // candidate index describing current c (-1 = unknown)
    for (int t = 0; t < N_STEPS; ++t) {
        float s;
        bool at_boundary = (c <= 0 || c >= GRID_N - 1);
        if (at_boundary) {
            s = 0.0f;
        } else if (pred >= 0 && cand_c[pred] == c) {
            s = cand_s[pred];
        } else {
            // rare fallback: position not in candidate table -> compute from global
            float a1 = fixv(psi[2 * (c + 1)]);
            float b1 = fixv(psi[2 * (c + 1) + 1]);
            float a0 = fixv(psi[2 * (c - 1)]);
            float b0 = fixv(psi[2 * (c - 1) + 1]);
            float p1 = fmaxf(__fdiv_rn(raw_prob(a1, b1), norm), 1e-12f);
            float p0 = fmaxf(__fdiv_rn(raw_prob(a0, b0), norm), 1e-12f);
            s = __fdiv_rn(__fsub_rn(logf(p1), logf(p0)), TWODXf);
        }
        float n = noise[t];
        float move = __fadd_rn(__fmul_rn(s, DTf), __fmul_rn(n, SQ2DTf));
        if (!isfinite(move)) move = 0.0f;
        int shift = host_f2i(__fdiv_rn(move, DXf));
        // next position's candidate identity: from boundary at step t it is
        // exactly cand[2t+parity] (bit-identical arithmetic in phase A)
        pred = at_boundary ? (2 * t + ((c != 0) ? 1 : 0)) : -1;
        c = wrap_clip(c, shift);
    }
    out[0] = x[c];
}

extern "C" void kernel_launch(void* const* d_in, const int* in_sizes, int n_in,
                              void* d_out, int out_size, void* d_ws, size_t ws_size,
                              hipStream_t stream) {
    const float* psi   = (const float*)d_in[0];
    const float* noise = (const float*)d_in[1];
    const float* x     = (const float*)d_in[2];
    const int*   c0    = (const int*)d_in[3];
    float* out = (float*)d_out;

    // ws layout: [0,64): counter + pad; [64, 64+SUMBLKS*8): partials
    unsigned int* counter = (unsigned int*)d_ws;
    double* partials = (double*)((char*)d_ws + 64);

    hipMemsetAsync(d_ws, 0, 64, stream);  // zero counter each call (graph-safe)
    qpe_fused_kernel<<<SUMBLKS + 1, 256, 0, stream>>>(psi, noise, x, c0,
                                                      counter, partials, out);
}

// Round 5
// 69.986 us; speedup vs baseline: 1.4495x; 1.4495x over previous
//
#include <hip/hip_runtime.h>
#include <cstdint>
#include <climits>

#define GRID_N 16777216
#define N_STEPS 100
#define NCAND (2 * N_STEPS + 1)   // 200 boundary-origin candidates + c0
#define NBLK 2048

// nan_to_num(psi, nan=0.0, posinf=1.0, neginf=-1.0)
__device__ __forceinline__ float fixv(float v) {
    if (isnan(v)) return 0.0f;
    if (isinf(v)) return v > 0.0f ? 1.0f : -1.0f;
    return v;
}

// psi0*psi0 + psi1*psi1 in strict f32, no FMA contraction (match host semantics)
__device__ __forceinline__ float raw_prob(float a, float b) {
    return __fadd_rn(__fmul_rn(a, a), __fmul_rn(b, b));
}

// x86 cvttss2si semantics: out-of-range or NaN -> INT_MIN (NOT GPU saturation)
__device__ __forceinline__ int host_f2i(float sf) {
    if (!(sf >= -2147483648.0f && sf < 2147483648.0f)) return INT_MIN;
    return (int)sf;
}

__device__ __forceinline__ int wrap_clip(int c, int shift) {
    int r = (int)((unsigned)c + (unsigned)shift);  // int32 wrapping add (XLA/NumPy)
    if (r < 0) r = 0;
    if (r > GRID_N - 1) r = GRID_N - 1;
    return r;
}

__global__ __launch_bounds__(256) void qpe_fused2_kernel(const float* __restrict__ psi,
                                                         const float* __restrict__ noise,
                                                         const float* __restrict__ x,
                                                         const int* __restrict__ c0p,
                                                         unsigned int* __restrict__ counter,
                                                         double* __restrict__ partials,
                                                         float* __restrict__ out) {
    const int tid = threadIdx.x;
    const int bid = blockIdx.x;

    const float DXf    = (float)(20.0 / (double)(GRID_N - 1));
    const float TWODXf = (float)(2.0 * (20.0 / (double)(GRID_N - 1)));
    const float DTf    = 0.01f;
    const float SQ2DTf = (float)0.14142135623730950488;  // np.sqrt(0.02) -> f32

    __shared__ double red[256];
    __shared__ int    cand_c[256];
    __shared__ float  cand_s[256];
    __shared__ float  norm_sh;

    // ---- block 0 only: issue candidate loads FIRST (latency hides under sum) ----
    // From a boundary b at step t (score==0 there), the next index is
    //   clip(wrap(b, int((noise[t]*sqrt2dt)/DX)))  -- a function of noise only.
    int myc = -1;
    float2 lo = make_float2(0.0f, 0.0f), hi = make_float2(0.0f, 0.0f);
    if (bid == 0 && tid < NCAND) {
        if (tid == NCAND - 1) {
            myc = *c0p;
        } else {
            int t = tid >> 1;
            float n = noise[t];
            // identical fp sequence to a walk step with s==0:
            float move = __fadd_rn(__fmul_rn(0.0f, DTf), __fmul_rn(n, SQ2DTf));
            if (!isfinite(move)) move = 0.0f;
            int shift = host_f2i(__fdiv_rn(move, DXf));
            int b = (tid & 1) ? (GRID_N - 1) : 0;
            myc = wrap_clip(b, shift);
        }
        if (myc > 0 && myc < GRID_N - 1) {
            lo = *(const float2*)(psi + 2 * myc - 2);  // psi[c-1][0..1]
            hi = *(const float2*)(psi + 2 * myc + 2);  // psi[c+1][0..1]
        }
    }

    // ---- every block: sum slice `bid` (bit-identical partition to r3) ----
    {
        const float4* psi4 = (const float4*)psi;
        const int n4 = GRID_N / 2;
        double acc = 0.0;
        for (int i = bid * 256 + tid; i < n4; i += NBLK * 256) {
            float4 v = psi4[i];
            acc += (double)raw_prob(fixv(v.x), fixv(v.y));
            acc += (double)raw_prob(fixv(v.z), fixv(v.w));
        }
        red[tid] = acc;
        __syncthreads();
        for (int s = 128; s > 0; s >>= 1) {   // fixed-order tree -> deterministic
            if (tid < s) red[tid] += red[tid + s];
            __syncthreads();
        }
        if (tid == 0) {
            // RELAXED agent atomics: sc1 path to the coherent point, NO wbl2/inv.
            __hip_atomic_store(&partials[bid], red[0], __ATOMIC_RELAXED,
                               __HIP_MEMORY_SCOPE_AGENT);
            // order: partial store acked at coherence point before counter bump
            asm volatile("s_waitcnt vmcnt(0)" ::: "memory");
            __hip_atomic_fetch_add(counter, 1u, __ATOMIC_RELAXED,
                                   __HIP_MEMORY_SCOPE_AGENT);
        }
    }
    if (bid != 0) return;

    // ---- block 0: wait for all partials (RELAXED polls -> no buffer_inv storm) ----
    if (tid == 0) {
        while (__hip_atomic_load(counter, __ATOMIC_RELAXED,
                                 __HIP_MEMORY_SCOPE_AGENT) < NBLK) {
            __builtin_amdgcn_s_sleep(16);
        }
    }
    __syncthreads();

    // ---- phase B: deterministic fixed-order f64 reduce (same order as r3) ----
    double acc = 0.0;
    for (int i = tid; i < NBLK; i += 256)
        acc += __hip_atomic_load(&partials[i], __ATOMIC_RELAXED,
                                 __HIP_MEMORY_SCOPE_AGENT);
    __syncthreads();   // red[] reuse: everyone done with sum-phase values
    red[tid] = acc;
    __syncthreads();
    for (int s = 128; s > 0; s >>= 1) {
        if (tid < s) red[tid] += red[tid + s];
        __syncthreads();
    }
    if (tid == 0) {
        float S = (float)red[0];
        norm_sh = __fadd_rn(__fmul_rn(S, DXf), 1e-8f);
    }
    __syncthreads();
    float norm = norm_sh;

    // ---- phase C: per-candidate score -> LDS table (exact ref fp sequence) ----
    float s_val = 0.0f;
    if (tid < NCAND && myc > 0 && myc < GRID_N - 1) {
        float a0 = fixv(lo.x), b0 = fixv(lo.y);
        float a1 = fixv(hi.x), b1 = fixv(hi.y);
        float p1 = fmaxf(__fdiv_rn(raw_prob(a1, b1), norm), 1e-12f);
        float p0 = fmaxf(__fdiv_rn(raw_prob(a0, b0), norm), 1e-12f);
        s_val = __fdiv_rn(__fsub_rn(logf(p1), logf(p0)), TWODXf);
    }
    cand_c[tid] = (tid < NCAND) ? myc : -1;
    cand_s[tid] = s_val;
    __syncthreads();

    if (tid != 0) return;

    // ---- phase D: sequential walk, LDS table lookups ----
    int c = cand_c[NCAND - 1];   // == *c0p
    int pred = NCAND - 1;        // candidate index describing current c (-1 = unknown)
    for (int t = 0; t < N_STEPS; ++t) {
        float s;
        bool at_boundary = (c <= 0 || c >= GRID_N - 1);
        if (at_boundary) {
            s = 0.0f;
        } else if (pred >= 0 && cand_c[pred] == c) {
            s = cand_s[pred];
        } else {
            // rare fallback: position not in candidate table -> compute from global
            float a1 = fixv(psi[2 * (c + 1)]);
            float b1 = fixv(psi[2 * (c + 1) + 1]);
            float a0 = fixv(psi[2 * (c - 1)]);
            float b0 = fixv(psi[2 * (c - 1) + 1]);
            float p1 = fmaxf(__fdiv_rn(raw_prob(a1, b1), norm), 1e-12f);
            float p0 = fmaxf(__fdiv_rn(raw_prob(a0, b0), norm), 1e-12f);
            s = __fdiv_rn(__fsub_rn(logf(p1), logf(p0)), TWODXf);
        }
        float n = noise[t];
        float move = __fadd_rn(__fmul_rn(s, DTf), __fmul_rn(n, SQ2DTf));
        if (!isfinite(move)) move = 0.0f;
        int shift = host_f2i(__fdiv_rn(move, DXf));
        // next position's candidate identity: from boundary at step t it is
        // exactly cand[2t+parity] (bit-identical arithmetic in phase A)
        pred = at_boundary ? (2 * t + ((c != 0) ? 1 : 0)) : -1;
        c = wrap_clip(c, shift);
    }
    out[0] = x[c];
}

extern "C" void kernel_launch(void* const* d_in, const int* in_sizes, int n_in,
                              void* d_out, int out_size, void* d_ws, size_t ws_size,
                              hipStream_t stream) {
    const float* psi   = (const float*)d_in[0];
    const float* noise = (const float*)d_in[1];
    const float* x     = (const float*)d_in[2];
    const int*   c0    = (const int*)d_in[3];
    float* out = (float*)d_out;

    // ws layout: [0,64): counter + pad; [64, 64+NBLK*8): partials
    unsigned int* counter = (unsigned int*)d_ws;
    double* partials = (double*)((char*)d_ws + 64);

    hipMemsetAsync(d_ws, 0, 64, stream);  // zero counter each call (graph-safe)
    qpe_fused2_kernel<<<NBLK, 256, 0, stream>>>(psi, noise, x, c0,
                                                counter, partials, out);
}

// Round 6
// 40.595 us; speedup vs baseline: 2.4990x; 1.7240x over previous
//
#include <hip/hip_runtime.h>
#include <cstdint>
#include <climits>

#define GRID_N 16777216
#define N_STEPS 100
#define NCAND (2 * N_STEPS + 1)   // 200 boundary-origin candidates + c0
#define NBLK 2048
#define THREADS 256
#define TTOT (NBLK * THREADS)     // 524288 threads; GRID_N/2 = 16*TTOT float4s

// nan_to_num(psi, nan=0.0, posinf=1.0, neginf=-1.0)
__device__ __forceinline__ float fixv(float v) {
    if (isnan(v)) return 0.0f;
    if (isinf(v)) return v > 0.0f ? 1.0f : -1.0f;
    return v;
}

// psi0*psi0 + psi1*psi1 in strict f32, no FMA contraction (match host semantics)
__device__ __forceinline__ float raw_prob(float a, float b) {
    return __fadd_rn(__fmul_rn(a, a), __fmul_rn(b, b));
}

// x86 cvttss2si semantics: out-of-range or NaN -> INT_MIN (NOT GPU saturation)
__device__ __forceinline__ int host_f2i(float sf) {
    if (!(sf >= -2147483648.0f && sf < 2147483648.0f)) return INT_MIN;
    return (int)sf;
}

__device__ __forceinline__ int wrap_clip(int c, int shift) {
    int r = (int)((unsigned)c + (unsigned)shift);  // int32 wrapping add (XLA/NumPy)
    if (r < 0) r = 0;
    if (r > GRID_N - 1) r = GRID_N - 1;
    return r;
}

__device__ __forceinline__ double pair_prob(float4 v) {
    return (double)raw_prob(fixv(v.x), fixv(v.y)) +
           (double)raw_prob(fixv(v.z), fixv(v.w));
}

__global__ __launch_bounds__(256) void qpe_sum_kernel(const float4* __restrict__ psi4,
                                                      double* __restrict__ partials) {
    const int tid = threadIdx.x;
    int i = blockIdx.x * THREADS + tid;
    double a0 = 0.0, a1 = 0.0, a2 = 0.0, a3 = 0.0;
#pragma unroll
    for (int k = 0; k < 4; ++k) {
        // 4 independent loads in flight per iteration (ILP for BW saturation)
        float4 v0 = psi4[i];
        float4 v1 = psi4[i + TTOT];
        float4 v2 = psi4[i + 2 * TTOT];
        float4 v3 = psi4[i + 3 * TTOT];
        i += 4 * TTOT;
        a0 += pair_prob(v0);
        a1 += pair_prob(v1);
        a2 += pair_prob(v2);
        a3 += pair_prob(v3);
    }
    double acc = (a0 + a1) + (a2 + a3);
    __shared__ double sm[256];
    sm[tid] = acc;
    __syncthreads();
    for (int s = 128; s > 0; s >>= 1) {   // fixed-order tree -> deterministic
        if (tid < s) sm[tid] += sm[tid + s];
        __syncthreads();
    }
    if (tid == 0) partials[blockIdx.x] = sm[0];
}

__global__ __launch_bounds__(256) void qpe_walk_kernel(const float* __restrict__ psi,
                                                       const float* __restrict__ noise,
                                                       const float* __restrict__ x,
                                                       const int* __restrict__ c0p,
                                                       const double* __restrict__ partials,
                                                       float* __restrict__ out) {
    const int tid = threadIdx.x;
    const float DXf    = (float)(20.0 / (double)(GRID_N - 1));
    const float TWODXf = (float)(2.0 * (20.0 / (double)(GRID_N - 1)));
    const float DTf    = 0.01f;
    const float SQ2DTf = (float)0.14142135623730950488;  // np.sqrt(0.02) -> f32

    __shared__ int    cand_c[256];
    __shared__ int    cand_next[256];
    __shared__ double red[256];
    __shared__ float  norm_sh;

    // ---- phase A: candidate positions; issue psi loads immediately ----
    // From a boundary b at step t (score==0 there), the next index is
    //   clip(wrap(b, int((noise[t]*sqrt2dt)/DX)))  -- a function of noise only.
    // tid = 2t + parity (parity 1 -> b = GRID-1); tid NCAND-1 -> c0 itself.
    int myc = -1;
    float2 lo = make_float2(0.0f, 0.0f), hi = make_float2(0.0f, 0.0f);
    if (tid < NCAND) {
        if (tid == NCAND - 1) {
            myc = *c0p;
        } else {
            int t = tid >> 1;
            float n = noise[t];
            // identical fp sequence to a walk step with s==0:
            float move = __fadd_rn(__fmul_rn(0.0f, DTf), __fmul_rn(n, SQ2DTf));
            if (!isfinite(move)) move = 0.0f;
            int shift = host_f2i(__fdiv_rn(move, DXf));
            int b = (tid & 1) ? (GRID_N - 1) : 0;
            myc = wrap_clip(b, shift);
        }
        if (myc > 0 && myc < GRID_N - 1) {
            lo = *(const float2*)(psi + 2 * myc - 2);  // psi[c-1][0..1]
            hi = *(const float2*)(psi + 2 * myc + 2);  // psi[c+1][0..1]
        }
    }

    // ---- phase B: deterministic fixed-order f64 reduce (8 independent loads) ----
    double acc = 0.0;
#pragma unroll
    for (int k = 0; k < NBLK / 256; ++k) acc += partials[tid + k * 256];
    red[tid] = acc;
    __syncthreads();
    for (int s = 128; s > 0; s >>= 1) {
        if (tid < s) red[tid] += red[tid + s];
        __syncthreads();
    }
    if (tid == 0) {
        float S = (float)red[0];
        norm_sh = __fadd_rn(__fmul_rn(S, DXf), 1e-8f);
    }
    __syncthreads();
    float norm = norm_sh;

    // ---- phase C: per-candidate score AND precomputed next position ----
    float s_val = 0.0f;
    int nxt = -2;   // sentinel: no precomputed next
    if (tid < NCAND && myc > 0 && myc < GRID_N - 1) {
        float a0 = fixv(lo.x), b0 = fixv(lo.y);
        float a1 = fixv(hi.x), b1 = fixv(hi.y);
        float p1 = fmaxf(__fdiv_rn(raw_prob(a1, b1), norm), 1e-12f);
        float p0 = fmaxf(__fdiv_rn(raw_prob(a0, b0), norm), 1e-12f);
        s_val = __fdiv_rn(__fsub_rn(logf(p1), logf(p0)), TWODXf);
        // candidate tid is occupied at step: (tid>>1)+1 for boundary-origin,
        // 0 for the c0 candidate; its move uses noise[that step].
        int nidx = (tid == NCAND - 1) ? 0 : (tid >> 1) + 1;
        if (nidx < N_STEPS) {
            float n = noise[nidx];
            // exact walk-step fp sequence with s = s_val:
            float move = __fadd_rn(__fmul_rn(s_val, DTf), __fmul_rn(n, SQ2DTf));
            if (!isfinite(move)) move = 0.0f;
            int shift = host_f2i(__fdiv_rn(move, DXf));
            nxt = wrap_clip(myc, shift);
        }
    }
    cand_c[tid] = (tid < NCAND) ? myc : -1;
    cand_next[tid] = nxt;
    __syncthreads();

    if (tid != 0) return;

    // ---- phase D: sequential walk via transition table ----
    int c = cand_c[NCAND - 1];   // == *c0p
    int ci = NCAND - 1;          // candidate id of current position (-1 = unknown)
    int t = 0;
    while (t < N_STEPS) {
        if (c <= 0 || c >= GRID_N - 1) {
            // boundary: s==0; landing position is candidate 2t+parity by construction
            int j = 2 * t + ((c != 0) ? 1 : 0);
            c = cand_c[j];
            ci = j;
            ++t;
        } else {
            int nx = (ci >= 0) ? cand_next[ci] : -2;
            if (nx != -2) {
                c = nx;        // precomputed with bit-identical fp ops
                ci = -1;
                ++t;
            } else {
                // rare fallback: interior position not in table -> global loads
                float a1v = fixv(psi[2 * (c + 1)]);
                float b1v = fixv(psi[2 * (c + 1) + 1]);
                float a0v = fixv(psi[2 * (c - 1)]);
                float b0v = fixv(psi[2 * (c - 1) + 1]);
                float p1 = fmaxf(__fdiv_rn(raw_prob(a1v, b1v), norm), 1e-12f);
                float p0 = fmaxf(__fdiv_rn(raw_prob(a0v, b0v), norm), 1e-12f);
                float s = __fdiv_rn(__fsub_rn(logf(p1), logf(p0)), TWODXf);
                float n = noise[t];
                float move = __fadd_rn(__fmul_rn(s, DTf), __fmul_rn(n, SQ2DTf));
                if (!isfinite(move)) move = 0.0f;
                int shift = host_f2i(__fdiv_rn(move, DXf));
                c = wrap_clip(c, shift);
                ci = -1;
                ++t;
            }
        }
    }
    out[0] = x[c];
}

extern "C" void kernel_launch(void* const* d_in, const int* in_sizes, int n_in,
                              void* d_out, int out_size, void* d_ws, size_t ws_size,
                              hipStream_t stream) {
    const float* psi   = (const float*)d_in[0];
    const float* noise = (const float*)d_in[1];
    const float* x     = (const float*)d_in[2];
    const int*   c0    = (const int*)d_in[3];
    float* out = (float*)d_out;

    double* partials = (double*)d_ws;

    qpe_sum_kernel<<<NBLK, THREADS, 0, stream>>>((const float4*)psi, partials);
    qpe_walk_kernel<<<1, THREADS, 0, stream>>>(psi, noise, x, c0, partials, out);
}